// Round 1
// 2631.143 us; speedup vs baseline: 1.1617x; 1.1617x over previous
//
#include <hip/hip_runtime.h>
#include <hip/hip_bf16.h>

typedef __hip_bfloat16 bf16;
typedef __bf16 bf16x8 __attribute__((ext_vector_type(8)));
typedef float f32x4 __attribute__((ext_vector_type(4)));

#define ROWS   32
#define HID    1024
#define PATH   256
#define NSTEP  50
#define P      1032   // LDS pitch (bf16) for inp(z) and th: 1024 + 8 -> uniform bank spread
#define SMEM_BYTES (2 * ROWS * P * 2)   // inp + th, bf16

__device__ __forceinline__ f32x4 mfma16(bf16x8 a, bf16x8 b, f32x4 c) {
    return __builtin_amdgcn_mfma_f32_16x16x32_bf16(a, b, c, 0, 0, 0);
}

__device__ __forceinline__ float tanh_fast(float x) {
    float e = __expf(2.0f * x);
    return 1.0f - 2.0f / (e + 1.0f);   // saturates, no NaN for finite x
}

__device__ __forceinline__ bf16x8 ldcvt8(const float* __restrict__ p) {
    f32x4 lo = *(const f32x4*)p;
    f32x4 hi = *(const f32x4*)(p + 4);
    bf16x8 r;
    #pragma unroll
    for (int j = 0; j < 4; j++) { r[j] = (__bf16)lo[j]; r[4 + j] = (__bf16)hi[j]; }
    return r;
}

// bf16x2 pack/unpack in a u32 (lo = elem0, hi = elem1)
__device__ __forceinline__ unsigned bfbits(float f) {
    __hip_bfloat16 h = __float2bfloat16(f);
    unsigned short u; __builtin_memcpy(&u, &h, 2);
    return (unsigned)u;
}
__device__ __forceinline__ unsigned bfpack2(float lo, float hi) {
    return bfbits(lo) | (bfbits(hi) << 16);
}
__device__ __forceinline__ float bflo(unsigned u) { return __uint_as_float(u << 16); }
__device__ __forceinline__ float bfhi(unsigned u) { return __uint_as_float(u & 0xffff0000u); }

// ---- pack f32 W[K][N] into bf16 MFMA B-fragment-linear layout ----
// fragment (kb, nb) = 1KB: lane l (lm=l&15, lq=l>>4) holds W[kb*32+lq*8+j][nb*16+lm]
__global__ void pack_frag(const float* __restrict__ src, bf16* __restrict__ dst, int N) {
    int kb = blockIdx.x, nb = blockIdx.y, l = threadIdx.x;
    int lm = l & 15, lq = l >> 4;
    bf16x8 v;
    #pragma unroll
    for (int j = 0; j < 8; j++)
        v[j] = __float2bfloat16(src[(size_t)(kb * 32 + lq * 8 + j) * N + nb * 16 + lm]);
    *(bf16x8*)(dst + ((size_t)(kb * gridDim.y + nb) * 64 + l) * 8) = v;
}

// ---- 32 x 64-col GEMM slice, software-pipelined ----
// acc[2][4] += lds_A(32 rows, pitch P) @ Wp cols [wave*64, +64); KB k-blocks of 32.
// Rolling w-slot refill (distance ~1 kb) + A-fragment ping-pong (distance 2 kb):
// each w[nt] is reloaded with the NEXT k-block's fragment right after its MFMAs
// consume it, so ~4-6 loads stay in flight per wave instead of ~0.
template<int KB>
__device__ __forceinline__ void gemm4p(const bf16* __restrict__ lds,
                                       const bf16* __restrict__ Wp,
                                       int wave, int lane, int rot, f32x4 (&acc)[2][4]) {
    static_assert((KB & (KB - 1)) == 0, "KB must be a power of two");
    const int lm = lane & 15, lq = lane >> 4;
    const bf16* a0b = lds + lm * P + lq * 8;
    const bf16* a1b = a0b + 16 * P;
    const int woff = wave * 2048 + lane * 8;     // element offset of this wave's frag row

    bf16x8 w[4], a0A, a1A, a0B, a1B;
    {
        const int k0 = rot & (KB - 1);
        const int k1 = (rot + 1) & (KB - 1);
        const bf16* wp = Wp + (size_t)k0 * 32768 + woff;
        #pragma unroll
        for (int nt = 0; nt < 4; nt++) w[nt] = *(const bf16x8*)(wp + nt * 512);
        a0A = *(const bf16x8*)(a0b + k0 * 32);
        a1A = *(const bf16x8*)(a1b + k0 * 32);
        a0B = *(const bf16x8*)(a0b + k1 * 32);
        a1B = *(const bf16x8*)(a1b + k1 * 32);
    }
    #pragma unroll 2
    for (int kb = 0; kb < KB; kb += 2) {
        // ---- even half: consume (a0A,a1A, w=data[kb]); refill w<-kb+1, aA<-kb+2
        const int kw1 = (kb + 1 + rot) & (KB - 1);
        const int ka1 = (kb + 2 + rot) & (KB - 1);
        const bf16* wp1 = Wp + (size_t)kw1 * 32768 + woff;
        acc[0][0] = mfma16(a0A, w[0], acc[0][0]);
        acc[1][0] = mfma16(a1A, w[0], acc[1][0]);
        w[0] = *(const bf16x8*)(wp1);
        acc[0][1] = mfma16(a0A, w[1], acc[0][1]);
        acc[1][1] = mfma16(a1A, w[1], acc[1][1]);
        w[1] = *(const bf16x8*)(wp1 + 512);
        acc[0][2] = mfma16(a0A, w[2], acc[0][2]);
        acc[1][2] = mfma16(a1A, w[2], acc[1][2]);
        w[2] = *(const bf16x8*)(wp1 + 1024);
        acc[0][3] = mfma16(a0A, w[3], acc[0][3]);
        acc[1][3] = mfma16(a1A, w[3], acc[1][3]);
        w[3] = *(const bf16x8*)(wp1 + 1536);
        a0A = *(const bf16x8*)(a0b + ka1 * 32);
        a1A = *(const bf16x8*)(a1b + ka1 * 32);
        // ---- odd half: consume (a0B,a1B, w=data[kb+1]); refill w<-kb+2, aB<-kb+3
        const int kw2 = ka1;                       // kb+2
        const int ka2 = (kb + 3 + rot) & (KB - 1); // wrap reads are in-range, values unused
        const bf16* wp2 = Wp + (size_t)kw2 * 32768 + woff;
        acc[0][0] = mfma16(a0B, w[0], acc[0][0]);
        acc[1][0] = mfma16(a1B, w[0], acc[1][0]);
        w[0] = *(const bf16x8*)(wp2);
        acc[0][1] = mfma16(a0B, w[1], acc[0][1]);
        acc[1][1] = mfma16(a1B, w[1], acc[1][1]);
        w[1] = *(const bf16x8*)(wp2 + 512);
        acc[0][2] = mfma16(a0B, w[2], acc[0][2]);
        acc[1][2] = mfma16(a1B, w[2], acc[1][2]);
        w[2] = *(const bf16x8*)(wp2 + 1024);
        acc[0][3] = mfma16(a0B, w[3], acc[0][3]);
        acc[1][3] = mfma16(a1B, w[3], acc[1][3]);
        w[3] = *(const bf16x8*)(wp2 + 1536);
        a0B = *(const bf16x8*)(a0b + ka2 * 32);
        a1B = *(const bf16x8*)(a1b + ka2 * 32);
    }
}

// ---------------- persistent fused CDE kernel ----------------
// 256 wgs (1/CU), 1024 threads = 16 waves. Each wg owns 32 batch rows; z persists
// in f32 registers (MFMA C-layout). Wave w computes cols [64w,64w+64).
// Register budget (128/lane for 16 waves/CU) is the binding constraint:
//   z 32 + cu_pk(bf16x2) 16 + acc 32 + w 16 + a 16 + bias 4 + addr ~10 ~= 126.
// c_u kept packed bf16; th pre-scaled by dt so GEMM2 accumulates straight into z.
__global__ __launch_bounds__(1024, 4) void cde_main(
    const float* __restrict__ x0,  const float* __restrict__ b_pe, const float* __restrict__ b_hi,
    const float* __restrict__ b1v, const float* __restrict__ b2v,  const float* __restrict__ b_ro,
    const bf16* __restrict__ WpeP, const bf16* __restrict__ WhiP,
    const bf16* __restrict__ W1zP, const bf16* __restrict__ W1uP,
    const bf16* __restrict__ W2P,  const bf16* __restrict__ WroP,
    float* __restrict__ out)
{
    extern __shared__ bf16 smem[];
    bf16* inp = smem;              // [32][P]  z staging (cols 0..1023); prologue: g staging
    bf16* th  = smem + ROWS * P;   // [32][P]  dt*tanh staging

    const int tid  = threadIdx.x;
    const int wave = tid >> 6;     // 0..15
    const int lane = tid & 63;
    const int lm   = lane & 15;
    const int lq   = lane >> 4;
    const int rot  = (blockIdx.x >> 3) & 31;   // distinct per CU within an XCD
    const long row0 = (long)blockIdx.x * ROWS;

    f32x4 z[2][4];        // row = mt*16+lq*4+r, col = wave*64+nt*16+lm
    f32x4 g[2];           // col = wave*16+lm
    uint2 cu_pk[2][4];    // g @ W1u, packed bf16x2 pairs (r0,r1 | r2,r3)

    // ---- merged prologue: g = x0@W_pe + b_pe ; z = x0@W_hi + b_hi ----
    #pragma unroll
    for (int nt = 0; nt < 4; nt++) {
        float b = b_hi[wave * 64 + nt * 16 + lm];
        #pragma unroll
        for (int r = 0; r < 4; r++) { z[0][nt][r] = b; z[1][nt][r] = b; }
    }
    {
        float b = b_pe[wave * 16 + lm];
        #pragma unroll
        for (int r = 0; r < 4; r++) { g[0][r] = b; g[1][r] = b; }
    }
    for (int kb = 0; kb < HID / 32; kb++) {
        int kbr = kb + rot; if (kbr >= 32) kbr -= 32;
        bf16x8 a0 = ldcvt8(x0 + (row0 +      lm) * HID + kbr * 32 + lq * 8);
        bf16x8 a1 = ldcvt8(x0 + (row0 + 16 + lm) * HID + kbr * 32 + lq * 8);
        const bf16* wp = WhiP + (((size_t)kbr * 64 + wave * 4) * 64 + lane) * 8;
        #pragma unroll
        for (int nt = 0; nt < 4; nt++) {
            bf16x8 bb = *(const bf16x8*)(wp + nt * 512);
            z[0][nt] = mfma16(a0, bb, z[0][nt]);
            z[1][nt] = mfma16(a1, bb, z[1][nt]);
        }
        bf16x8 pb = *(const bf16x8*)(WpeP + (((size_t)kbr * 16 + wave) * 64 + lane) * 8);
        g[0] = mfma16(a0, pb, g[0]);
        g[1] = mfma16(a1, pb, g[1]);
    }

    // ---- c_u = g @ W1u (once), then compress to bf16 pairs ----
    #pragma unroll
    for (int mt = 0; mt < 2; mt++)
        #pragma unroll
        for (int r = 0; r < 4; r++)
            inp[(mt * 16 + lq * 4 + r) * P + wave * 16 + lm] = __float2bfloat16(g[mt][r]);
    __syncthreads();
    {
        f32x4 cu[2][4];
        #pragma unroll
        for (int mt = 0; mt < 2; mt++)
            #pragma unroll
            for (int nt = 0; nt < 4; nt++)
                #pragma unroll
                for (int r = 0; r < 4; r++) cu[mt][nt][r] = 0.0f;
        for (int kb = 0; kb < PATH / 32; kb++) {
            const bf16* wp = W1uP + (((size_t)kb * 64 + wave * 4) * 64 + lane) * 8;
            bf16x8 a0 = *(const bf16x8*)(inp + lm * P + kb * 32 + lq * 8);
            bf16x8 a1 = *(const bf16x8*)(inp + (16 + lm) * P + kb * 32 + lq * 8);
            #pragma unroll
            for (int nt = 0; nt < 4; nt++) {
                bf16x8 bb = *(const bf16x8*)(wp + nt * 512);
                cu[0][nt] = mfma16(a0, bb, cu[0][nt]);
                cu[1][nt] = mfma16(a1, bb, cu[1][nt]);
            }
        }
        #pragma unroll
        for (int mt = 0; mt < 2; mt++)
            #pragma unroll
            for (int nt = 0; nt < 4; nt++)
                cu_pk[mt][nt] = make_uint2(bfpack2(cu[mt][nt][0], cu[mt][nt][1]),
                                           bfpack2(cu[mt][nt][2], cu[mt][nt][3]));
    }
    __syncthreads();

    const float DT = 1.0f / (float)NSTEP;

    // hoisted biases, packed: lo = b1, hi = DT*b2 (bf16 rounding ~5e-5 abs, negligible)
    unsigned b12[4];
    #pragma unroll
    for (int nt = 0; nt < 4; nt++)
        b12[nt] = bfpack2(b1v[wave * 64 + nt * 16 + lm],
                          DT * b2v[wave * 64 + nt * 16 + lm]);

    // ---- 50 fused steps ----
    for (int s = 0; s < NSTEP; s++) {
        float t = DT * (float)(s + 1);

        // A-phase: refresh bf16 z staging
        #pragma unroll
        for (int mt = 0; mt < 2; mt++)
            #pragma unroll
            for (int nt = 0; nt < 4; nt++)
                #pragma unroll
                for (int r = 0; r < 4; r++)
                    inp[(mt * 16 + lq * 4 + r) * P + wave * 64 + nt * 16 + lm] =
                        __float2bfloat16(z[mt][nt][r]);
        __syncthreads();

        // B-phase: th = dt * tanh(z @ W1z + t*c_u + b1)
        {
            f32x4 acc[2][4];
            #pragma unroll
            for (int mt = 0; mt < 2; mt++)
                #pragma unroll
                for (int nt = 0; nt < 4; nt++) {
                    float b1 = bflo(b12[nt]);
                    unsigned px = cu_pk[mt][nt].x, py = cu_pk[mt][nt].y;
                    acc[mt][nt][0] = fmaf(t, bflo(px), b1);
                    acc[mt][nt][1] = fmaf(t, bfhi(px), b1);
                    acc[mt][nt][2] = fmaf(t, bflo(py), b1);
                    acc[mt][nt][3] = fmaf(t, bfhi(py), b1);
                }
            gemm4p<HID / 32>(inp, W1zP, wave, lane, rot, acc);
            #pragma unroll
            for (int mt = 0; mt < 2; mt++)
                #pragma unroll
                for (int nt = 0; nt < 4; nt++)
                    #pragma unroll
                    for (int r = 0; r < 4; r++)
                        th[(mt * 16 + lq * 4 + r) * P + wave * 64 + nt * 16 + lm] =
                            __float2bfloat16(DT * tanh_fast(acc[mt][nt][r]));
        }
        __syncthreads();

        // C-phase: z += dt*b2 ; z = (dt*h) @ W2 accumulated directly into z
        {
            #pragma unroll
            for (int mt = 0; mt < 2; mt++)
                #pragma unroll
                for (int nt = 0; nt < 4; nt++) {
                    float db = bfhi(b12[nt]);   // DT*b2
                    #pragma unroll
                    for (int r = 0; r < 4; r++) z[mt][nt][r] += db;
                }
            gemm4p<HID / 32>(th, W2P, wave, lane, rot, z);
        }
        // no barrier: next A-write (inp) is safe — all waves passed the pre-C barrier
        // only after finishing their B-phase inp-reads (incl. drained prefetches);
        // th hazards separated by the next loop's post-A barrier.
    }

    // ---- epilogue: out = z @ W_ro + b_ro (f32 store) ----
    #pragma unroll
    for (int mt = 0; mt < 2; mt++)
        #pragma unroll
        for (int nt = 0; nt < 4; nt++)
            #pragma unroll
            for (int r = 0; r < 4; r++)
                inp[(mt * 16 + lq * 4 + r) * P + wave * 64 + nt * 16 + lm] =
                    __float2bfloat16(z[mt][nt][r]);
    __syncthreads();
    {
        f32x4 acc[2][4];
        #pragma unroll
        for (int nt = 0; nt < 4; nt++) {
            float b = b_ro[wave * 64 + nt * 16 + lm];
            #pragma unroll
            for (int r = 0; r < 4; r++) { acc[0][nt][r] = b; acc[1][nt][r] = b; }
        }
        gemm4p<HID / 32>(inp, WroP, wave, lane, rot, acc);
        #pragma unroll
        for (int mt = 0; mt < 2; mt++)
            #pragma unroll
            for (int nt = 0; nt < 4; nt++)
                #pragma unroll
                for (int r = 0; r < 4; r++)
                    out[(row0 + mt * 16 + lq * 4 + r) * HID + wave * 64 + nt * 16 + lm] =
                        acc[mt][nt][r];
    }
}

extern "C" void kernel_launch(void* const* d_in, const int* in_sizes, int n_in,
                              void* d_out, int out_size, void* d_ws, size_t ws_size,
                              hipStream_t stream) {
    (void)in_sizes; (void)n_in; (void)out_size; (void)ws_size;
    const float* x0  = (const float*)d_in[0];
    const float* Wpe = (const float*)d_in[1];
    const float* bpe = (const float*)d_in[2];
    const float* Whi = (const float*)d_in[3];
    const float* bhi = (const float*)d_in[4];
    const float* W1  = (const float*)d_in[5];
    const float* b1  = (const float*)d_in[6];
    const float* W2  = (const float*)d_in[7];
    const float* b2  = (const float*)d_in[8];
    const float* Wro = (const float*)d_in[9];
    const float* bro = (const float*)d_in[10];

    bf16* ws   = (bf16*)d_ws;
    bf16* WpeP = ws;                          // 256*1024
    bf16* WhiP = WpeP + 256 * 1024;           // 1024*1024
    bf16* W1zP = WhiP + 1024 * 1024;          // 1024*1024 (W1 rows 0..1023)
    bf16* W1uP = W1zP + 1024 * 1024;          // 256*1024  (W1 rows 1024..1279)
    bf16* W2P  = W1uP + 256 * 1024;           // 1024*1024
    bf16* WroP = W2P  + 1024 * 1024;          // 1024*1024

    hipLaunchKernelGGL(pack_frag, dim3(1024 / 32, 256 / 16), dim3(64), 0, stream, Wpe, WpeP, 256);
    hipLaunchKernelGGL(pack_frag, dim3(1024 / 32, 1024 / 16), dim3(64), 0, stream, Whi, WhiP, 1024);
    hipLaunchKernelGGL(pack_frag, dim3(1024 / 32, 1024 / 16), dim3(64), 0, stream, W1, W1zP, 1024);
    hipLaunchKernelGGL(pack_frag, dim3(256 / 32, 1024 / 16), dim3(64), 0, stream,
                       W1 + (size_t)1024 * 1024, W1uP, 1024);
    hipLaunchKernelGGL(pack_frag, dim3(1024 / 32, 1024 / 16), dim3(64), 0, stream, W2, W2P, 1024);
    hipLaunchKernelGGL(pack_frag, dim3(1024 / 32, 1024 / 16), dim3(64), 0, stream, Wro, WroP, 1024);

    hipFuncSetAttribute((const void*)cde_main,
                        hipFuncAttributeMaxDynamicSharedMemorySize, SMEM_BYTES);
    hipLaunchKernelGGL(cde_main, dim3(8192 / ROWS), dim3(1024), SMEM_BYTES, stream,
                       x0, bpe, bhi, b1, b2, bro, WpeP, WhiP, W1zP, W1uP, W2P, WroP,
                       (float*)d_out);
}